// Round 9
// baseline (42.650 us; speedup 1.0000x reference)
//
#include <hip/hip_runtime.h>
#include <hip/hip_bf16.h>

typedef __attribute__((ext_vector_type(4))) float f32x4;
typedef __attribute__((ext_vector_type(8))) short bf16x8;

#define N_NEI 64
#define D_IN  128
#define D_HID 128

union BF8 { bf16x8 v; __hip_bfloat162 h[4]; unsigned u[4]; };

__device__ __forceinline__ bf16x8 pack8(const float4& a, const float4& b) {
  BF8 r;
  r.h[0] = __float22bfloat162_rn(float2{a.x, a.y});
  r.h[1] = __float22bfloat162_rn(float2{a.z, a.w});
  r.h[2] = __float22bfloat162_rn(float2{b.x, b.y});
  r.h[3] = __float22bfloat162_rn(float2{b.z, b.w});
  return r.v;
}

// Converter: W_mlp, W_comb -> bf16, PRE-SWIZZLED so k1/k2 can DMA them into
// LDS linearly (global_load_lds writes base+lane*16; swizzle must live in the
// global layout — guide m173 pattern).
//  wmlp_bf:  32KB, byte(j,d0)  = j*256 + ((d0*2) ^ ((j&7)<<4)),  j<128, d0 multiple of 8
//  wcomb_bf: 128KB, 8 slabs of 32 cols: byte = s*16384 + jr*512 + ((d0*2) ^ ((jr&7)<<4))
__global__ __launch_bounds__(256)
void conv_w(const float* __restrict__ Wmlp, const float* __restrict__ Wcomb,
            unsigned short* __restrict__ wmlp_bf, unsigned short* __restrict__ wcomb_bf) {
  int t = blockIdx.x * 256 + threadIdx.x;
  if (t < 2048) {                       // W_mlp: 16384 elems, 8 per thread
    int j = t >> 4, d0 = (t & 15) * 8;
    const float* p = Wmlp + j * 128 + d0;
    float4 a = *(const float4*)p, b = *(const float4*)(p + 4);
    int byte = j * 256 + ((d0 * 2) ^ ((j & 7) << 4));
    *(bf16x8*)((char*)wmlp_bf + byte) = pack8(a, b);
  } else if (t < 2048 + 8192) {         // W_comb: 65536 elems, 8 per thread
    int c = t - 2048;
    int jg = c >> 5, d0 = (c & 31) * 8;
    const float* p = Wcomb + jg * 256 + d0;
    float4 a = *(const float4*)p, b = *(const float4*)(p + 4);
    int s = jg >> 5, jr = jg & 31;
    int byte = s * 16384 + jr * 512 + ((d0 * 2) ^ ((jr & 7) << 4));
    *(bf16x8*)((char*)wcomb_bf + byte) = pack8(a, b);
  }
}

// Kernel 1: pooled[b][j] = max_n relu(neigh[b,n,:]·W_mlp[j,:] + b_mlp[j]), masked rows -> 0.
// One block = 4 waves; each wave owns ONE batch row. DUAL M-TILE loop (round-8
// win): 32 rows/iter, every B-fragment LDS read feeds two MFMAs. This round:
// W staging via global_load_lds DMA of the pre-converted/pre-swizzled bf16 W
// (32KB, 8 issues, no VGPR round-trip, no cvt) — shorter prologue.
__global__ __launch_bounds__(256, 2)
void k1_pool(const float* __restrict__ neigh, const unsigned short* __restrict__ wmlp_bf,
             const float* __restrict__ bmlp, unsigned short* __restrict__ pooled) {
  __shared__ unsigned short Wl[D_HID * D_IN];  // 32KB bf16, swizzled (layout from converter)
  __shared__ float pscr[4][D_HID];             // per-wave epilogue scratch

  const int tid = threadIdx.x;
  const int l = tid & 63;
  const int w = tid >> 6;
  const int lr = l & 15;   // A row-in-tile / B col-in-tile
  const int lg = l >> 4;   // k-group

  const int b = blockIdx.x * 4 + w;     // this wave's batch row
  const float* rowbase = neigh + (size_t)b * N_NEI * D_IN;

  // 0. issue iter-0's 32-row loads first — overlap with W DMA below
  float4 pf[16];
  {
    const float* ra = rowbase + (size_t)lr * D_IN + lg * 8;
    const float* rb = rowbase + (size_t)(16 + lr) * D_IN + lg * 8;
    #pragma unroll
    for (int ks = 0; ks < 4; ++ks) {
      pf[2 * ks]      = *(const float4*)(ra + ks * 32);
      pf[2 * ks + 1]  = *(const float4*)(ra + ks * 32 + 4);
      pf[8 + 2 * ks]  = *(const float4*)(rb + ks * 32);
      pf[9 + 2 * ks]  = *(const float4*)(rb + ks * 32 + 4);
    }
  }

  // 1. DMA-stage pre-swizzled bf16 W -> LDS (wave-uniform LDS base, lane*16 auto)
  {
    const char* wsrc = (const char*)wmlp_bf;
    #pragma unroll
    for (int i = 0; i < 8; ++i) {
      int off = (i * 4 + w) * 1024;
      __builtin_amdgcn_global_load_lds(
        (const __attribute__((address_space(1))) unsigned int*)(wsrc + off + l * 16),
        (__attribute__((address_space(3))) unsigned int*)((char*)Wl + off),
        16, 0, 0);
    }
  }

  float bml[8];
  #pragma unroll
  for (int t = 0; t < 8; ++t) bml[t] = bmlp[t * 16 + lr];

  __syncthreads();   // drains DMA + pf

  float pmax[8];
  #pragma unroll
  for (int t = 0; t < 8; ++t) pmax[t] = 0.f;  // exact: masked entries are 0, relu >= 0

  #pragma unroll 1
  for (int it = 0; it < 2; ++it) {      // 32-neighbor dual M-tile per iteration
    // 2. consume pf: fp32->bf16 fragments + fp32 row-sums for the mask
    bf16x8 afA[4], afB[4];
    float rsA = 0.f, rsB = 0.f;
    #pragma unroll
    for (int ks = 0; ks < 4; ++ks) {
      float4 a0 = pf[2 * ks],     a1 = pf[2 * ks + 1];
      float4 b0 = pf[8 + 2 * ks], b1 = pf[9 + 2 * ks];
      rsA += a0.x + a0.y + a0.z + a0.w + a1.x + a1.y + a1.z + a1.w;
      rsB += b0.x + b0.y + b0.z + b0.w + b1.x + b1.y + b1.z + b1.w;
      afA[ks] = pack8(a0, a1);
      afB[ks] = pack8(b0, b1);
    }

    // 3. issue iter-1's loads — in flight under this iteration's MFMA section
    if (it == 0) {
      const float* ra = rowbase + (size_t)(32 + lr) * D_IN + lg * 8;
      const float* rb = rowbase + (size_t)(48 + lr) * D_IN + lg * 8;
      #pragma unroll
      for (int ks = 0; ks < 4; ++ks) {
        pf[2 * ks]      = *(const float4*)(ra + ks * 32);
        pf[2 * ks + 1]  = *(const float4*)(ra + ks * 32 + 4);
        pf[8 + 2 * ks]  = *(const float4*)(rb + ks * 32);
        pf[9 + 2 * ks]  = *(const float4*)(rb + ks * 32 + 4);
      }
    }

    rsA += __shfl_xor(rsA, 16); rsA += __shfl_xor(rsA, 32);
    rsB += __shfl_xor(rsB, 16); rsB += __shfl_xor(rsB, 32);
    unsigned maskA = (unsigned)(__ballot(rsA == 0.0f) & 0xFFFFull);
    unsigned maskB = (unsigned)(__ballot(rsB == 0.0f) & 0xFFFFull);

    // 4. two passes of 4 N-tiles; each B read feeds both M-tiles
    #pragma unroll 1
    for (int p = 0; p < 2; ++p) {
      f32x4 accA[4], accB[4];
      #pragma unroll
      for (int tt = 0; tt < 4; ++tt) {
        accA[tt] = (f32x4){0.f, 0.f, 0.f, 0.f};
        accB[tt] = (f32x4){0.f, 0.f, 0.f, 0.f};
      }

      #pragma unroll
      for (int tt = 0; tt < 4; ++tt) {
        #pragma unroll
        for (int ks = 0; ks < 4; ++ks) {
          int jr = (p * 4 + tt) * 16 + lr;
          int d0 = ks * 32 + lg * 8;
          bf16x8 bf = *(const bf16x8*)((const char*)Wl + jr * 256 + ((d0 * 2) ^ ((jr & 7) << 4)));
          accA[tt] = __builtin_amdgcn_mfma_f32_16x16x32_bf16(afA[ks], bf, accA[tt], 0, 0, 0);
          accB[tt] = __builtin_amdgcn_mfma_f32_16x16x32_bf16(afB[ks], bf, accB[tt], 0, 0, 0);
        }
      }

      // relu + bias + mask, fold into running per-lane max
      #pragma unroll
      for (int tt = 0; tt < 4; ++tt) {
        #pragma unroll
        for (int r = 0; r < 4; ++r) {
          int row = lg * 4 + r;          // D-layout: row = (l>>4)*4 + reg
          float vA = fmaxf(accA[tt][r] + bml[p * 4 + tt], 0.f);
          float vB = fmaxf(accB[tt][r] + bml[p * 4 + tt], 0.f);
          if ((maskA >> row) & 1u) vA = 0.f;
          if ((maskB >> row) & 1u) vB = 0.f;
          pmax[p * 4 + tt] = fmaxf(pmax[p * 4 + tt], fmaxf(vA, vB));
        }
      }
    }
  }

  // cross-lane-group max (rows live in lg groups)
  #pragma unroll
  for (int t = 0; t < 8; ++t) {
    pmax[t] = fmaxf(pmax[t], __shfl_xor(pmax[t], 16));
    pmax[t] = fmaxf(pmax[t], __shfl_xor(pmax[t], 32));
  }

  // epilogue: transpose via per-wave LDS scratch, packed bf16x2 store (256B/wave)
  if (l < 16) {
    #pragma unroll
    for (int t = 0; t < 8; ++t) pscr[w][t * 16 + l] = pmax[t];
  }
  __syncthreads();   // once per kernel; also orders pscr write->read
  float2 pv = *(const float2*)&pscr[w][2 * l];
  __hip_bfloat162 h2 = __float22bfloat162_rn(pv);
  ((unsigned*)(pooled + (size_t)b * D_HID))[l] = *(unsigned*)&h2;
}

// Kernel 2: out[b][j] = relu([input|pooled][b,:]·W_comb[j,:] + b_comb[j])
// Block = 64 rows x 32 cols, grid 512 -> 2 blocks/CU. W slab (16KB bf16,
// pre-swizzled) DMA'd via global_load_lds.
__global__ __launch_bounds__(256, 2)
void k2_comb(const float* __restrict__ inp, const unsigned short* __restrict__ pooled,
             const unsigned short* __restrict__ wcomb_bf, const float* __restrict__ bcomb,
             float* __restrict__ out) {
  __shared__ unsigned short Wl[32 * 256];  // 16KB: 32 output cols x K=256, swizzled

  const int tid = threadIdx.x;
  const int l = tid & 63;
  const int w = tid >> 6;
  const int mchunk = blockIdx.x >> 3;   // 64-row chunk, 0..63
  const int c8     = blockIdx.x & 7;    // 32-col slab
  const int lr = l & 15;
  const int lg = l >> 4;

  const int row = mchunk * 64 + w * 16 + lr;

  // 0. issue A loads first — overlap with W DMA
  float4 a0[4], a1[4];
  #pragma unroll
  for (int ks = 0; ks < 4; ++ks) {   // k < 128: fp32 input
    const float* p = inp + (size_t)row * 128 + ks * 32 + lg * 8;
    a0[ks] = *(const float4*)p;
    a1[ks] = *(const float4*)(p + 4);
  }
  bf16x8 af[8];
  #pragma unroll
  for (int ks = 4; ks < 8; ++ks) {   // k >= 128: pooled already bf16
    af[ks] = *(const bf16x8*)(pooled + (size_t)row * 128 + (ks - 4) * 32 + lg * 8);
  }

  // 1. DMA-stage the 16KB slab
  {
    const char* wsrc = (const char*)wcomb_bf + c8 * 16384;
    #pragma unroll
    for (int i = 0; i < 4; ++i) {
      int off = (i * 4 + w) * 1024;
      __builtin_amdgcn_global_load_lds(
        (const __attribute__((address_space(1))) unsigned int*)(wsrc + off + l * 16),
        (__attribute__((address_space(3))) unsigned int*)((char*)Wl + off),
        16, 0, 0);
    }
  }

  float bcl[2];
  #pragma unroll
  for (int t = 0; t < 2; ++t) bcl[t] = bcomb[c8 * 32 + t * 16 + lr];

  #pragma unroll
  for (int ks = 0; ks < 4; ++ks) af[ks] = pack8(a0[ks], a1[ks]);

  __syncthreads();

  f32x4 acc[2];
  #pragma unroll
  for (int t = 0; t < 2; ++t) acc[t] = (f32x4){0.f, 0.f, 0.f, 0.f};
  #pragma unroll
  for (int t = 0; t < 2; ++t) {
    #pragma unroll
    for (int ks = 0; ks < 8; ++ks) {
      int jr = t * 16 + lr;
      int d0 = ks * 32 + lg * 8;
      bf16x8 bf = *(const bf16x8*)((const char*)Wl + jr * 512 + ((d0 * 2) ^ ((jr & 7) << 4)));
      acc[t] = __builtin_amdgcn_mfma_f32_16x16x32_bf16(af[ks], bf, acc[t], 0, 0, 0);
    }
  }

  #pragma unroll
  for (int t = 0; t < 2; ++t) {
    #pragma unroll
    for (int r = 0; r < 4; ++r) {
      int ro = mchunk * 64 + w * 16 + lg * 4 + r;
      int co = c8 * 32 + t * 16 + lr;
      float v = acc[t][r] + bcl[t];
      out[(size_t)ro * 256 + co] = fmaxf(v, 0.f);
    }
  }
}

extern "C" void kernel_launch(void* const* d_in, const int* in_sizes, int n_in,
                              void* d_out, int out_size, void* d_ws, size_t ws_size,
                              hipStream_t stream) {
  const float* inp   = (const float*)d_in[0];
  const float* neigh = (const float*)d_in[1];
  const float* Wmlp  = (const float*)d_in[2];
  const float* bmlp  = (const float*)d_in[3];
  const float* Wcomb = (const float*)d_in[4];
  const float* bcomb = (const float*)d_in[5];
  float* out = (float*)d_out;

  unsigned short* pooled   = (unsigned short*)d_ws;                        // 1MB
  unsigned short* wmlp_bf  = (unsigned short*)((char*)d_ws + (1 << 20));   // 32KB
  unsigned short* wcomb_bf = (unsigned short*)((char*)d_ws + (1 << 20) + 32768);  // 128KB

  conv_w<<<40, 256, 0, stream>>>(Wmlp, Wcomb, wmlp_bf, wcomb_bf);
  k1_pool<<<1024, 256, 0, stream>>>(neigh, wmlp_bf, bmlp, pooled);
  k2_comb<<<512, 256, 0, stream>>>(inp, pooled, wcomb_bf, bcomb, out);
}

// Round 10
// 38.505 us; speedup vs baseline: 1.1077x; 1.1077x over previous
//
#include <hip/hip_runtime.h>
#include <hip/hip_bf16.h>

typedef __attribute__((ext_vector_type(4))) float f32x4;
typedef __attribute__((ext_vector_type(8))) short bf16x8;

#define N_NEI 64
#define D_IN  128
#define D_HID 128

union BF8 { bf16x8 v; __hip_bfloat162 h[4]; unsigned u[4]; };

__device__ __forceinline__ bf16x8 pack8(const float4& a, const float4& b) {
  BF8 r;
  r.h[0] = __float22bfloat162_rn(float2{a.x, a.y});
  r.h[1] = __float22bfloat162_rn(float2{a.z, a.w});
  r.h[2] = __float22bfloat162_rn(float2{b.x, b.y});
  r.h[3] = __float22bfloat162_rn(float2{b.z, b.w});
  return r.v;
}

// Kernel 1: pooled[b][j] = max_n relu(neigh[b,n,:]·W_mlp[j,:] + b_mlp[j]), masked rows -> 0.
// Round-9 lesson: DMA/converter lost to launch overhead — reverted to R8 base.
// This round: WORK x2 PER WAVE. 512 blocks (one resident dispatch round at any
// VGPR), each wave owns TWO batch rows sequentially -> W staged once per 8 rows,
// 4 dual-M-tile iterations per wave with depth-1 prefetch chained continuously
// across the row boundary (steady-state pipeline 3/4 of lifetime instead of 1/2).
// Inner dual-M-tile loop identical to R8 (best measured: every B-fragment LDS
// read feeds two MFMAs).
__global__ __launch_bounds__(256, 2)
void k1_pool(const float* __restrict__ neigh, const float* __restrict__ Wmlp,
             const float* __restrict__ bmlp, unsigned short* __restrict__ pooled) {
  __shared__ unsigned short Wl[D_HID * D_IN];  // 32KB bf16, row j = 256B, XOR-swizzled
  __shared__ float pscr[8][D_HID];             // 8 pooled rows (block = 8 batch rows)

  const int tid = threadIdx.x;
  const int l = tid & 63;
  const int w = tid >> 6;
  const int lr = l & 15;   // A row-in-tile / B col-in-tile
  const int lg = l >> 4;   // k-group

  const int bbase = blockIdx.x * 8 + w * 2;   // this wave's 2 rows: bbase, bbase+1

  // 0. issue step-0 loads (row bbase, neighbors 0..31) — overlap with W staging
  float4 pf[16];
  {
    const float* ra = neigh + (size_t)bbase * N_NEI * D_IN + (size_t)lr * D_IN + lg * 8;
    #pragma unroll
    for (int ks = 0; ks < 4; ++ks) {
      pf[2 * ks]      = *(const float4*)(ra + ks * 32);
      pf[2 * ks + 1]  = *(const float4*)(ra + ks * 32 + 4);
      pf[8 + 2 * ks]  = *(const float4*)(ra + 16 * D_IN + ks * 32);
      pf[9 + 2 * ks]  = *(const float4*)(ra + 16 * D_IN + ks * 32 + 4);
    }
  }

  // 1. stage W_mlp -> LDS bf16 (swizzled: byte = j*256 + ((d*2) ^ ((j&7)<<4)))
  const float4* W4 = (const float4*)Wmlp;
  #pragma unroll
  for (int it = 0; it < 8; ++it) {
    int f8 = it * 256 + tid;            // 8-float chunk id, 0..2047
    int j  = f8 >> 4;                   // row 0..127
    int d0 = (f8 & 15) * 8;             // col start
    float4 a = W4[f8 * 2];
    float4 bb = W4[f8 * 2 + 1];
    int byte = j * 256 + ((d0 * 2) ^ ((j & 7) << 4));
    *(bf16x8*)((char*)Wl + byte) = pack8(a, bb);
  }

  float bml[8];
  #pragma unroll
  for (int t = 0; t < 8; ++t) bml[t] = bmlp[t * 16 + lr];

  __syncthreads();   // drains staging (and pf) — pf ready at loop entry

  #pragma unroll 1
  for (int rr = 0; rr < 2; ++rr) {      // this wave's 2 batch rows
    float pmax[8];
    #pragma unroll
    for (int t = 0; t < 8; ++t) pmax[t] = 0.f;  // exact: masked rows are 0, relu >= 0

    #pragma unroll 1
    for (int it = 0; it < 2; ++it) {    // 32-neighbor dual M-tile per iteration
      // 2. consume pf: fp32->bf16 fragments + fp32 row-sums for the mask
      bf16x8 afA[4], afB[4];
      float rsA = 0.f, rsB = 0.f;
      #pragma unroll
      for (int ks = 0; ks < 4; ++ks) {
        float4 a0 = pf[2 * ks],     a1 = pf[2 * ks + 1];
        float4 b0 = pf[8 + 2 * ks], b1 = pf[9 + 2 * ks];
        rsA += a0.x + a0.y + a0.z + a0.w + a1.x + a1.y + a1.z + a1.w;
        rsB += b0.x + b0.y + b0.z + b0.w + b1.x + b1.y + b1.z + b1.w;
        afA[ks] = pack8(a0, a1);
        afB[ks] = pack8(b0, b1);
      }

      // 3. issue next step's loads (chained across the row boundary)
      {
        int q1 = rr * 2 + it + 1;       // next step 1..4; 4 = done
        if (q1 < 4) {
          const float* nb = neigh + (size_t)(bbase + (q1 >> 1)) * N_NEI * D_IN
                            + (size_t)((q1 & 1) * 32 + lr) * D_IN + lg * 8;
          #pragma unroll
          for (int ks = 0; ks < 4; ++ks) {
            pf[2 * ks]      = *(const float4*)(nb + ks * 32);
            pf[2 * ks + 1]  = *(const float4*)(nb + ks * 32 + 4);
            pf[8 + 2 * ks]  = *(const float4*)(nb + 16 * D_IN + ks * 32);
            pf[9 + 2 * ks]  = *(const float4*)(nb + 16 * D_IN + ks * 32 + 4);
          }
        }
      }

      rsA += __shfl_xor(rsA, 16); rsA += __shfl_xor(rsA, 32);
      rsB += __shfl_xor(rsB, 16); rsB += __shfl_xor(rsB, 32);
      unsigned maskA = (unsigned)(__ballot(rsA == 0.0f) & 0xFFFFull);
      unsigned maskB = (unsigned)(__ballot(rsB == 0.0f) & 0xFFFFull);

      // 4. two passes of 4 N-tiles; each B read feeds both M-tiles
      #pragma unroll 1
      for (int p = 0; p < 2; ++p) {
        f32x4 accA[4], accB[4];
        #pragma unroll
        for (int tt = 0; tt < 4; ++tt) {
          accA[tt] = (f32x4){0.f, 0.f, 0.f, 0.f};
          accB[tt] = (f32x4){0.f, 0.f, 0.f, 0.f};
        }

        #pragma unroll
        for (int tt = 0; tt < 4; ++tt) {
          #pragma unroll
          for (int ks = 0; ks < 4; ++ks) {
            int jr = (p * 4 + tt) * 16 + lr;
            int d0 = ks * 32 + lg * 8;
            bf16x8 bf = *(const bf16x8*)((const char*)Wl + jr * 256 + ((d0 * 2) ^ ((jr & 7) << 4)));
            accA[tt] = __builtin_amdgcn_mfma_f32_16x16x32_bf16(afA[ks], bf, accA[tt], 0, 0, 0);
            accB[tt] = __builtin_amdgcn_mfma_f32_16x16x32_bf16(afB[ks], bf, accB[tt], 0, 0, 0);
          }
        }

        // relu + bias + mask, fold into running per-lane max
        #pragma unroll
        for (int tt = 0; tt < 4; ++tt) {
          #pragma unroll
          for (int r = 0; r < 4; ++r) {
            int row = lg * 4 + r;        // D-layout: row = (l>>4)*4 + reg
            float vA = fmaxf(accA[tt][r] + bml[p * 4 + tt], 0.f);
            float vB = fmaxf(accB[tt][r] + bml[p * 4 + tt], 0.f);
            if ((maskA >> row) & 1u) vA = 0.f;
            if ((maskB >> row) & 1u) vB = 0.f;
            pmax[p * 4 + tt] = fmaxf(pmax[p * 4 + tt], fmaxf(vA, vB));
          }
        }
      }
    }

    // finish row rr: cross-lane-group max, park in LDS
    #pragma unroll
    for (int t = 0; t < 8; ++t) {
      pmax[t] = fmaxf(pmax[t], __shfl_xor(pmax[t], 16));
      pmax[t] = fmaxf(pmax[t], __shfl_xor(pmax[t], 32));
    }
    if (l < 16) {
      #pragma unroll
      for (int t = 0; t < 8; ++t) pscr[w * 2 + rr][t * 16 + l] = pmax[t];
    }
  }

  __syncthreads();   // once per kernel; orders pscr write->read
  // epilogue: thread tid writes 4 cols of pooled row (tid>>5)
  {
    int prow = tid >> 5;             // 0..7
    int c4   = (tid & 31) * 4;       // 0..124
    float4 pv = *(const float4*)&pscr[prow][c4];
    __hip_bfloat162 h0 = __float22bfloat162_rn(float2{pv.x, pv.y});
    __hip_bfloat162 h1 = __float22bfloat162_rn(float2{pv.z, pv.w});
    uint2 u;
    u.x = *(unsigned*)&h0;
    u.y = *(unsigned*)&h1;
    *(uint2*)(pooled + (size_t)(blockIdx.x * 8 + prow) * D_HID + c4) = u;
  }
}

// Kernel 2: out[b][j] = relu([input|pooled][b,:]·W_comb[j,:] + b_comb[j])
// Block = 64 rows x 64 cols (quarter of output cols), K = 256.  (round-8 verbatim)
__global__ __launch_bounds__(256, 2)
void k2_comb(const float* __restrict__ inp, const unsigned short* __restrict__ pooled,
             const float* __restrict__ Wcomb, const float* __restrict__ bcomb,
             float* __restrict__ out) {
  __shared__ unsigned short Wl[64 * 256];  // 32KB: 64 output cols x K=256, row = 512B, swizzled

  const int tid = threadIdx.x;
  const int l = tid & 63;
  const int w = tid >> 6;
  const int mchunk = blockIdx.x >> 2;   // 64-row chunk, 0..63
  const int colq   = blockIdx.x & 3;    // 64-col quarter
  const int lr = l & 15;
  const int lg = l >> 4;

  const int row = mchunk * 64 + w * 16 + lr;

  // 0. issue A loads first — overlap with W staging
  float4 a0[4], a1[4];
  #pragma unroll
  for (int ks = 0; ks < 4; ++ks) {   // k < 128: fp32 input
    const float* p = inp + (size_t)row * 128 + ks * 32 + lg * 8;
    a0[ks] = *(const float4*)p;
    a1[ks] = *(const float4*)(p + 4);
  }
  bf16x8 af[8];
  #pragma unroll
  for (int ks = 4; ks < 8; ++ks) {   // k >= 128: pooled already bf16
    af[ks] = *(const bf16x8*)(pooled + (size_t)row * 128 + (ks - 4) * 32 + lg * 8);
  }

  // 1. stage W quarter -> LDS bf16 (swizzled)
  const float4* W4 = (const float4*)Wcomb;
  #pragma unroll
  for (int it = 0; it < 8; ++it) {
    int c  = it * 256 + tid;            // 8-float chunk, 0..2047
    int jr = c >> 5;                    // 0..63
    int d0 = (c & 31) * 8;
    int gidx = ((colq * 64 + jr) * 256 + d0) >> 2;  // float4 index into W_comb
    float4 a = W4[gidx];
    float4 bb = W4[gidx + 1];
    int byte = jr * 512 + ((d0 * 2) ^ ((jr & 7) << 4));
    *(bf16x8*)((char*)Wl + byte) = pack8(a, bb);
  }

  float bcl[4];
  #pragma unroll
  for (int t = 0; t < 4; ++t) bcl[t] = bcomb[colq * 64 + t * 16 + lr];

  #pragma unroll
  for (int ks = 0; ks < 4; ++ks) af[ks] = pack8(a0[ks], a1[ks]);

  __syncthreads();

  f32x4 acc[4];
  #pragma unroll
  for (int t = 0; t < 4; ++t) acc[t] = (f32x4){0.f, 0.f, 0.f, 0.f};
  #pragma unroll
  for (int t = 0; t < 4; ++t) {
    #pragma unroll
    for (int ks = 0; ks < 8; ++ks) {
      int jr = t * 16 + lr;
      int d0 = ks * 32 + lg * 8;
      bf16x8 bf = *(const bf16x8*)((const char*)Wl + jr * 512 + ((d0 * 2) ^ ((jr & 7) << 4)));
      acc[t] = __builtin_amdgcn_mfma_f32_16x16x32_bf16(af[ks], bf, acc[t], 0, 0, 0);
    }
  }

  #pragma unroll
  for (int t = 0; t < 4; ++t) {
    #pragma unroll
    for (int r = 0; r < 4; ++r) {
      int ro = mchunk * 64 + w * 16 + lg * 4 + r;
      int co = colq * 64 + t * 16 + lr;
      float v = acc[t][r] + bcl[t];
      out[(size_t)ro * 256 + co] = fmaxf(v, 0.f);
    }
  }
}

extern "C" void kernel_launch(void* const* d_in, const int* in_sizes, int n_in,
                              void* d_out, int out_size, void* d_ws, size_t ws_size,
                              hipStream_t stream) {
  const float* inp   = (const float*)d_in[0];
  const float* neigh = (const float*)d_in[1];
  const float* Wmlp  = (const float*)d_in[2];
  const float* bmlp  = (const float*)d_in[3];
  const float* Wcomb = (const float*)d_in[4];
  const float* bcomb = (const float*)d_in[5];
  float* out = (float*)d_out;
  unsigned short* pooled = (unsigned short*)d_ws;  // [4096][128] bf16, 1 MB

  k1_pool<<<512, 256, 0, stream>>>(neigh, Wmlp, bmlp, pooled);
  k2_comb<<<256, 256, 0, stream>>>(inp, pooled, Wcomb, bcomb, out);
}